// Round 7
// baseline (795.738 us; speedup 1.0000x reference)
//
#include <hip/hip_runtime.h>
#include <hip/hip_bf16.h>

#define NN 100000
#define EE 1600000
#define GG 64
#define HH 128
#define LL 3
#define BN_EPS 1e-5f
#define NBUCK 196          // ceil(NN/512)
#define BCAP 12288         // bucket capacity (mean 8163, +45 sigma safe)
#define PART_CHUNK 8192

typedef __attribute__((ext_vector_type(8))) short bf16x8;
typedef __attribute__((ext_vector_type(4))) float f32x4;
typedef unsigned int uint32;

__device__ __forceinline__ float bflo(uint32 u) { return __uint_as_float(u << 16); }
__device__ __forceinline__ float bfhi(uint32 u) { return __uint_as_float(u & 0xffff0000u); }
__device__ __forceinline__ unsigned short f2bf(float f) {
    uint32 x = __float_as_uint(f);
    uint32 r = (x + 0x7fffu + ((x >> 16) & 1u)) >> 16;
    return (unsigned short)r;
}
__device__ __forceinline__ float bf2f(unsigned short u) { return __uint_as_float(((uint32)u) << 16); }
__device__ __forceinline__ void acc2(float2& a, uint32 u) { a.x += bflo(u); a.y += bfhi(u); }
// dequant-accumulate 4 unsigned uint8 channels with per-row scale
__device__ __forceinline__ void accq(float4& a, uint32 u, float sc) {
    a.x += sc * (float)(u & 0xffu);
    a.y += sc * (float)((u >> 8) & 0xffu);
    a.z += sc * (float)((u >> 16) & 0xffu);
    a.w += sc * (float)(u >> 24);
}
// dequant-accumulate 4 signed int8 channels with per-row scale
__device__ __forceinline__ void accqs(float4& a, uint32 u, float sc) {
    a.x += sc * (float)((int)(u << 24) >> 24);
    a.y += sc * (float)((int)(u << 16) >> 24);
    a.z += sc * (float)((int)(u << 8) >> 24);
    a.w += sc * (float)((int)u >> 24);
}

// ---------------- bucketed edge partition (fixed-capacity buckets) ----------------
__global__ __launch_bounds__(256) void partition_kernel(
    const int* __restrict__ src, const int* __restrict__ dst,
    int* __restrict__ bcnt, uint32* __restrict__ part) {
    __shared__ int cnt[NBUCK];
    __shared__ int loff[NBUCK + 1];
    __shared__ int gpos[NBUCK];
    __shared__ int lcur[NBUCK];
    __shared__ uint32 buf[PART_CHUNK];
    int tid = threadIdx.x;
    int base = blockIdx.x * PART_CHUNK;
    int n = min(PART_CHUNK, EE - base);
    for (int i = tid; i < NBUCK; i += 256) { cnt[i] = 0; lcur[i] = 0; }
    __syncthreads();
    for (int i = tid; i < n; i += 256) atomicAdd(&cnt[dst[base + i] >> 9], 1);
    __syncthreads();
    if (tid == 0) {
        int acc = 0;
        for (int b = 0; b < NBUCK; ++b) { loff[b] = acc; acc += cnt[b]; }
        loff[NBUCK] = acc;
    }
    __syncthreads();
    if (tid < NBUCK && cnt[tid] > 0) gpos[tid] = atomicAdd(&bcnt[tid], cnt[tid]);
    __syncthreads();
    for (int i = tid; i < n; i += 256) {
        int d = dst[base + i];
        int s = src[base + i];
        int b = d >> 9;
        int slot = atomicAdd(&lcur[b], 1);
        buf[loff[b] + slot] = (uint32)s | ((uint32)(d & 511) << 17);
    }
    __syncthreads();
    for (int i = tid; i < n; i += 256) {
        int lo = 0, hi = NBUCK;
        while (hi - lo > 1) { int mid = (lo + hi) >> 1; if (loff[mid] <= i) lo = mid; else hi = mid; }
        part[(size_t)lo * BCAP + gpos[lo] + (i - loff[lo])] = buf[i];
    }
}

// ---------------- build per-bucket CSR + col (all in LDS) ----------------
__global__ __launch_bounds__(256) void build_col_kernel(
    const uint32* __restrict__ part, const int* __restrict__ bcnt,
    int* __restrict__ col, int2* __restrict__ rowpair) {
    __shared__ int ldeg[512];
    __shared__ int loffn[512];
    __shared__ int lcur[512];
    __shared__ int pscan[256];
    __shared__ int cl[BCAP];
    int b = blockIdx.x;
    int tid = threadIdx.x;
    int node0 = b << 9;
    int nn = min(node0 + 512, NN) - node0;
    int cnt = bcnt[b];
    int base = b * BCAP;
    const uint32* pp = part + (size_t)base;
    for (int i = tid; i < 512; i += 256) { ldeg[i] = 0; lcur[i] = 0; }
    __syncthreads();
    for (int i = tid; i < cnt; i += 256) atomicAdd(&ldeg[pp[i] >> 17], 1);
    __syncthreads();
    int t2 = tid * 2;
    int a0 = ldeg[t2], a1 = ldeg[t2 + 1];
    int ps = a0 + a1;
    pscan[tid] = ps;
    __syncthreads();
    for (int off = 1; off < 256; off <<= 1) {
        int v = (tid >= off) ? pscan[tid - off] : 0;
        __syncthreads();
        pscan[tid] += v;
        __syncthreads();
    }
    int eo = pscan[tid] - ps;       // exclusive over pairs
    loffn[t2] = eo;
    loffn[t2 + 1] = eo + a0;
    if (t2 < nn)     rowpair[node0 + t2]     = make_int2(base + eo, base + eo + a0);
    if (t2 + 1 < nn) rowpair[node0 + t2 + 1] = make_int2(base + eo + a0, base + eo + a0 + a1);
    __syncthreads();
    for (int i = tid; i < cnt; i += 256) {
        uint32 v = pp[i];
        int dl = (int)(v >> 17);
        int pos = atomicAdd(&lcur[dl], 1);
        cl[loffn[dl] + pos] = (int)(v & 0x1FFFFu);
    }
    __syncthreads();
    for (int i = tid; i < cnt; i += 256) col[base + i] = cl[i];
}

// ---------------- graph counts ----------------
__global__ void counts_kernel(const int* __restrict__ batch, float* __restrict__ cnt, int n) {
    __shared__ int h[GG];
    int tid = threadIdx.x;
    if (tid < GG) h[tid] = 0;
    __syncthreads();
    int i = blockIdx.x * 256 + tid;
    if (i < n) atomicAdd(&h[batch[i]], 1);
    __syncthreads();
    if (tid < GG && h[tid]) atomicAdd(&cnt[tid], (float)h[tid]);
}

// ---------------- x -> int8 row-quantized (symmetric, per-row scale) ----------------
__global__ void x_to_i8_kernel(const float* __restrict__ x, unsigned short* __restrict__ x8,
                               float* __restrict__ sc0) {
    int row = (blockIdx.x * 256 + threadIdx.x) >> 6;
    int lane = threadIdx.x & 63;
    if (row >= NN) return;
    float2 v = ((const float2*)x)[(size_t)row * 64 + lane];
    float m = fmaxf(fabsf(v.x), fabsf(v.y));
#pragma unroll
    for (int off = 1; off < 64; off <<= 1) m = fmaxf(m, __shfl_xor(m, off));
    float scale = m * (1.f / 127.f);
    float inv = (m > 0.f) ? 127.f / m : 0.f;
    int b0 = __float2int_rn(v.x * inv);
    int b1 = __float2int_rn(v.y * inv);
    unsigned short pk = (unsigned short)((b0 & 0xff) | ((b1 & 0xff) << 8));
    x8[(size_t)row * 64 + lane] = pk;
    if (lane == 0) sc0[row] = scale;
}

#define MAT_STRIDE 16384   // ushort elements per frag-ordered matrix

// frag-order weights: [br(2)][l(3)][mat(2)][nt(8)][ks(4)][lane(64)][j(8)]
__global__ void convert_w_kernel(const float* __restrict__ W1a, const float* __restrict__ W2a,
                                 const float* __restrict__ W1b, const float* __restrict__ W2b,
                                 unsigned short* __restrict__ out) {
    int t = blockIdx.x * 256 + threadIdx.x;
    if (t >= 24576) return;
    int lane = t & 63;
    int r = t >> 6;
    int ks = r & 3; r >>= 2;
    int nt = r & 7; r >>= 3;
    int mat = r & 1; r >>= 1;
    int l = r % 3, br = r / 3;
    const float* W = br ? (mat ? W2b : W1b) : (mat ? W2a : W1a);
    const float* Wl = W + (size_t)l * 128 * 128;
    int n0 = nt * 16 + (lane & 15);
    int k0 = ks * 32 + (lane >> 4) * 8;
    unsigned short tmp[8];
#pragma unroll
    for (int j = 0; j < 8; ++j) tmp[j] = f2bf(Wl[(size_t)(k0 + j) * 128 + n0]);
    size_t seq = (size_t)(br * 3 + l) * 2 + mat;
    size_t off = (((seq * 8 + nt) * 4 + ks) * 64 + (size_t)lane) * 8;
    *(uint4*)(out + off) = *(const uint4*)tmp;
}

// ---------------- layer-0 gather on int8 x: g0[i] = bf16( x[i] + sum_j x[j] ) ----------------
// 2 edge-slots per wave; 32 lanes x 1 dword (4 ch) per edge row (128 B)
__global__ void gather0_kernel(const uint32* __restrict__ x8, const float* __restrict__ sc0,
                               const int2* __restrict__ rowpair, const int* __restrict__ col,
                               uint2* __restrict__ out) {
    int gw = (blockIdx.x * blockDim.x + threadIdx.x) >> 6;
    int lane = threadIdx.x & 63;
    if (gw >= NN) return;
    int slot = lane >> 5;      // 0..1
    int c = lane & 31;         // dword idx: channels 4c..4c+3
    float4 acc = {0.f, 0.f, 0.f, 0.f};
    if (slot == 0) accqs(acc, x8[(size_t)gw * 32 + c], sc0[gw]);
    int2 be = rowpair[gw];
    int beg = be.x, end = be.y;
    int e = beg;
    for (; e + 4 <= end; e += 4) {
        int j0 = col[e + slot], j1 = col[e + 2 + slot];
        uint32 u0 = x8[(size_t)j0 * 32 + c]; float s0 = sc0[j0];
        uint32 u1 = x8[(size_t)j1 * 32 + c]; float s1 = sc0[j1];
        accqs(acc, u0, s0);
        accqs(acc, u1, s1);
    }
    for (; e + 2 <= end; e += 2) {
        int j = col[e + slot];
        accqs(acc, x8[(size_t)j * 32 + c], sc0[j]);
    }
    if (e < end && slot == 0) {
        int j = col[e];
        accqs(acc, x8[(size_t)j * 32 + c], sc0[j]);
    }
    acc.x += __shfl_xor(acc.x, 32);
    acc.y += __shfl_xor(acc.y, 32);
    acc.z += __shfl_xor(acc.z, 32);
    acc.w += __shfl_xor(acc.w, 32);
    if (slot == 0) {
        uint2 o;
        o.x = (uint32)f2bf(acc.x) | ((uint32)f2bf(acc.y) << 16);
        o.y = (uint32)f2bf(acc.z) | ((uint32)f2bf(acc.w) << 16);
        out[(size_t)gw * 32 + c] = o;
    }
}

// ---------------- dual-branch gather on uint8 concat [N,256] rows + per-row scales ----------
__global__ void gather_dual_kernel(const uint32* __restrict__ y8, const float* __restrict__ scales,
                                   const int2* __restrict__ rowpair, const int* __restrict__ col,
                                   const float* __restrict__ stats,
                                   const float* __restrict__ ga, const float* __restrict__ bta,
                                   const float* __restrict__ gb, const float* __restrict__ btb,
                                   int lprev, uint2* __restrict__ out) {
    int gw = (blockIdx.x * blockDim.x + threadIdx.x) >> 6;
    int lane = threadIdx.x & 63;
    if (gw >= NN) return;
    int br = lane >> 5;
    const float* st = stats + (size_t)(lprev * 2 + br) * 256;
    const float* gmp = (br ? gb : ga) + lprev * 128;
    const float* btp = (br ? btb : bta) + lprev * 128;
    int cc0 = (lane * 4) & 127;
    float A[4], B[4];
#pragma unroll
    for (int j = 0; j < 4; ++j) {
        float s = st[cc0 + j], sq = st[128 + cc0 + j];
        float mu = s * (1.f / NN);
        float var = sq * (1.f / NN) - mu * mu;
        float a = gmp[cc0 + j] * rsqrtf(var + BN_EPS);
        A[j] = a;
        B[j] = btp[cc0 + j] - mu * a;
    }
    float4 accA = {0.f, 0.f, 0.f, 0.f};
    float4 accB = {0.f, 0.f, 0.f, 0.f};
    {   // self
        uint32 us = y8[(size_t)gw * 64 + lane];
        float ss = scales[gw * 2 + br];
        accq(accA, us, ss);
    }
    int2 be = rowpair[gw];
    int beg = be.x, end = be.y;
    float degp1 = (float)(end - beg + 1);
    int e = beg;
    for (; e + 4 <= end; e += 4) {
        int j0 = col[e], j1 = col[e + 1], j2 = col[e + 2], j3 = col[e + 3];
        uint32 u0 = y8[(size_t)j0 * 64 + lane]; float s0 = scales[j0 * 2 + br];
        uint32 u1 = y8[(size_t)j1 * 64 + lane]; float s1 = scales[j1 * 2 + br];
        uint32 u2 = y8[(size_t)j2 * 64 + lane]; float s2 = scales[j2 * 2 + br];
        uint32 u3 = y8[(size_t)j3 * 64 + lane]; float s3 = scales[j3 * 2 + br];
        accq(accA, u0, s0);
        accq(accB, u1, s1);
        accq(accA, u2, s2);
        accq(accB, u3, s3);
    }
    for (; e < end; ++e) {
        int j = col[e];
        uint32 u = y8[(size_t)j * 64 + lane];
        float s = scales[j * 2 + br];
        accq(accA, u, s);
    }
    float o0 = A[0] * (accA.x + accB.x) + B[0] * degp1;
    float o1 = A[1] * (accA.y + accB.y) + B[1] * degp1;
    float o2 = A[2] * (accA.z + accB.z) + B[2] * degp1;
    float o3 = A[3] * (accA.w + accB.w) + B[3] * degp1;
    uint2 o;
    o.x = (uint32)f2bf(o0) | ((uint32)f2bf(o1) << 16);
    o.y = (uint32)f2bf(o2) | ((uint32)f2bf(o3) << 16);
    out[(size_t)gw * 64 + lane] = o;
}

// ---------------- fused dual-branch MLP (64-row blocks; all weights from global/L2) --------
// blockIdx.y = branch. quant=1: write uint8 rows + per-row scale. quant=0: bf16 concat rows.
__global__ __launch_bounds__(256, 4) void mlp_dual_kernel(
    const unsigned short* __restrict__ X, int in_stride, int in_off_mul,
    const unsigned short* __restrict__ wf_all,
    const float* __restrict__ b1a, const float* __restrict__ b1b,
    const float* __restrict__ b2a, const float* __restrict__ b2b,
    int l, int quant,
    unsigned short* __restrict__ Y, unsigned char* __restrict__ Y8,
    float* __restrict__ scales, float* __restrict__ stats, int n) {
    __shared__ unsigned short hs[4][16][136];      // 17.4 KB, per-wave transpose buffer
    __shared__ float ssum[128], ssq[128];

    int br = blockIdx.y;
    const unsigned short* Wf = wf_all + (size_t)(br * 3 + l) * 2 * MAT_STRIDE;
    const float* b1 = (br ? b1b : b1a) + l * 128;
    const float* b2 = (br ? b2b : b2a) + l * 128;
    float* statsp = stats + (size_t)(l * 2 + br) * 256;
    int in_off = in_off_mul * br;

    int tid = threadIdx.x;
    int wv = tid >> 6, lane = tid & 63;
    int quad = lane >> 4, l16 = lane & 15;

    if (tid < 128) { ssum[tid] = 0.f; ssq[tid] = 0.f; }
    __syncthreads();

    const bf16x8* w1g = (const bf16x8*)Wf;
    const bf16x8* w2g = (const bf16x8*)(Wf + MAT_STRIDE);
    unsigned char* hs8 = (unsigned char*)&hs[wv][0][0];   // 16 rows x 144B stride

    int row0 = blockIdx.x * 64 + wv * 16;

    bf16x8 aF[4];
    {
        int r = row0 + l16;
        if (r >= n) r = n - 1;
        const unsigned short* xrow = X + (size_t)r * in_stride + in_off;
#pragma unroll
        for (int ks = 0; ks < 4; ++ks) aF[ks] = *(const bf16x8*)(xrow + ks * 32 + quad * 8);
    }

    f32x4 acc1[8];
#pragma unroll
    for (int nt = 0; nt < 8; ++nt) {
        bf16x8 bf0 = w1g[(nt * 4 + 0) * 64 + lane];
        bf16x8 bf1 = w1g[(nt * 4 + 1) * 64 + lane];
        bf16x8 bf2 = w1g[(nt * 4 + 2) * 64 + lane];
        bf16x8 bf3 = w1g[(nt * 4 + 3) * 64 + lane];
        f32x4 c = {0.f, 0.f, 0.f, 0.f};
        c = __builtin_amdgcn_mfma_f32_16x16x32_bf16(aF[0], bf0, c, 0, 0, 0);
        c = __builtin_amdgcn_mfma_f32_16x16x32_bf16(aF[1], bf1, c, 0, 0, 0);
        c = __builtin_amdgcn_mfma_f32_16x16x32_bf16(aF[2], bf2, c, 0, 0, 0);
        c = __builtin_amdgcn_mfma_f32_16x16x32_bf16(aF[3], bf3, c, 0, 0, 0);
        acc1[nt] = c;
    }

#pragma unroll
    for (int nt = 0; nt < 8; ++nt) {
        int c0 = nt * 16 + l16;
        float bb = b1[c0];
#pragma unroll
        for (int r = 0; r < 4; ++r) {
            float v = fmaxf(acc1[nt][r] + bb, 0.f);
            hs[wv][quad * 4 + r][c0] = f2bf(v);
        }
    }

    bf16x8 aH[4];
#pragma unroll
    for (int ks = 0; ks < 4; ++ks)
        aH[ks] = *(const bf16x8*)(&hs[wv][l16][ks * 32 + quad * 8]);

    f32x4 acc2_[8];
#pragma unroll
    for (int nt = 0; nt < 8; ++nt) {
        bf16x8 bf0 = w2g[(nt * 4 + 0) * 64 + lane];
        bf16x8 bf1 = w2g[(nt * 4 + 1) * 64 + lane];
        bf16x8 bf2 = w2g[(nt * 4 + 2) * 64 + lane];
        bf16x8 bf3 = w2g[(nt * 4 + 3) * 64 + lane];
        f32x4 c = {0.f, 0.f, 0.f, 0.f};
        c = __builtin_amdgcn_mfma_f32_16x16x32_bf16(aH[0], bf0, c, 0, 0, 0);
        c = __builtin_amdgcn_mfma_f32_16x16x32_bf16(aH[1], bf1, c, 0, 0, 0);
        c = __builtin_amdgcn_mfma_f32_16x16x32_bf16(aH[2], bf2, c, 0, 0, 0);
        c = __builtin_amdgcn_mfma_f32_16x16x32_bf16(aH[3], bf3, c, 0, 0, 0);
        acc2_[nt] = c;
    }

    // bias2 + relu + OOB-zero + BN stats (in place)
#pragma unroll
    for (int nt = 0; nt < 8; ++nt) {
        int c0 = nt * 16 + l16;
        float bb = b2[c0];
        float s = 0.f, sq = 0.f;
#pragma unroll
        for (int r = 0; r < 4; ++r) {
            float v = fmaxf(acc2_[nt][r] + bb, 0.f);
            if (row0 + quad * 4 + r >= n) v = 0.f;
            acc2_[nt][r] = v;
            s += v; sq += v * v;
        }
        s += __shfl_xor(s, 16); s += __shfl_xor(s, 32);
        sq += __shfl_xor(sq, 16); sq += __shfl_xor(sq, 32);
        if (quad == 0) { atomicAdd(&ssum[c0], s); atomicAdd(&ssq[c0], sq); }
    }

    if (!quant) {
        // bf16 concat output (layer 2 -> pooling)
#pragma unroll
        for (int nt = 0; nt < 8; ++nt) {
            int c0 = nt * 16 + l16;
#pragma unroll
            for (int r = 0; r < 4; ++r) hs[wv][quad * 4 + r][c0] = f2bf(acc2_[nt][r]);
        }
        int grow = row0 + l16;
        if (grow < n) {
#pragma unroll
            for (int j = 0; j < 4; ++j) {
                uint4 v = *(const uint4*)(&hs[wv][l16][quad * 32 + j * 8]);
                *(uint4*)(Y + (size_t)grow * 256 + br * 128 + quad * 32 + j * 8) = v;
            }
        }
    } else {
        // uint8 row-quantized output (values >= 0 post-relu)
#pragma unroll
        for (int r = 0; r < 4; ++r) {
            float m = acc2_[0][r];
#pragma unroll
            for (int nt = 1; nt < 8; ++nt) m = fmaxf(m, acc2_[nt][r]);
            m = fmaxf(m, __shfl_xor(m, 1));
            m = fmaxf(m, __shfl_xor(m, 2));
            m = fmaxf(m, __shfl_xor(m, 4));
            m = fmaxf(m, __shfl_xor(m, 8));
            float sc = m * (1.f / 255.f);
            float inv = (m > 0.f) ? 255.f / m : 0.f;
            int grow = row0 + quad * 4 + r;
            if (l16 == r && grow < n) scales[grow * 2 + br] = sc;
#pragma unroll
            for (int nt = 0; nt < 8; ++nt) {
                uint32 u = (uint32)__float2int_rn(acc2_[nt][r] * inv);
                hs8[(quad * 4 + r) * 144 + nt * 16 + l16] = (unsigned char)u;
            }
        }
        int grow = row0 + l16;
        if (grow < n) {
            *(uint4*)(Y8 + (size_t)grow * 256 + br * 128 + quad * 32) =
                *(const uint4*)(hs8 + l16 * 144 + quad * 32);
            *(uint4*)(Y8 + (size_t)grow * 256 + br * 128 + quad * 32 + 16) =
                *(const uint4*)(hs8 + l16 * 144 + quad * 32 + 16);
        }
    }
    __syncthreads();
    if (tid < 128) {
        atomicAdd(&statsp[tid], ssum[tid]);
        atomicAdd(&statsp[128 + tid], ssq[tid]);
    }
}

// ---------------- dual pooling from concat buffer ----------------
#define POOL_CHUNK 128
__global__ void pool_dual_kernel(const unsigned short* __restrict__ h,
                                 const float* __restrict__ stats,
                                 const float* __restrict__ ga, const float* __restrict__ bta,
                                 const float* __restrict__ gb, const float* __restrict__ btb,
                                 const int* __restrict__ batch,
                                 float* __restrict__ poolA, float* __restrict__ poolB, int n) {
    int t = threadIdx.x;       // 256 threads: ch t of concat row
    int br = t >> 7, cc = t & 127;
    const float* st = stats + (size_t)(2 * 2 + br) * 256;   // layer 2 stats
    float s = st[cc], sq = st[128 + cc];
    float mu = s * (1.f / NN);
    float var = sq * (1.f / NN) - mu * mu;
    float gm = (br ? gb : ga)[2 * 128 + cc];
    float a = gm * rsqrtf(var + BN_EPS);
    float b = (br ? btb : bta)[2 * 128 + cc] - mu * a;
    float* pool = br ? poolB : poolA;

    int i0 = blockIdx.x * POOL_CHUNK;
    if (i0 >= n) return;
    int i1 = min(i0 + POOL_CHUNK, n);
    float acc = 0.f;
    int cur = batch[i0];
    for (int i = i0; i < i1; ++i) {
        int g = batch[i];
        if (g != cur) {
            atomicAdd(&pool[cur * 128 + cc], acc);
            acc = 0.f;
            cur = g;
        }
        acc += a * bf2f(h[(size_t)i * 256 + t]) + b;
    }
    atomicAdd(&pool[cur * 128 + cc], acc);
}

// ---------------- bilinear discriminator (mean inline) ----------------
__global__ void disc_kernel(const float* __restrict__ poolB, const float* __restrict__ cnt,
                            const float* __restrict__ W, const float* __restrict__ db,
                            float* __restrict__ out) {
    int g = blockIdx.x, e = threadIdx.x;    // 128 threads
    __shared__ float rs[128], rh[128];
    float invc = 1.f / fmaxf(cnt[g], 1.f);
    int gs = (g == 32) ? 30 : (63 - g);
    float invcs = 1.f / fmaxf(cnt[gs], 1.f);
    const float* a = poolB + g * 128;
    float t = 0.f;
    for (int d = 0; d < 128; ++d) t += a[d] * W[d * 128 + e];
    t *= invc;
    rs[e] = t * poolB[g * 128 + e] * invc;
    rh[e] = t * poolB[gs * 128 + e] * invcs;
    __syncthreads();
    for (int s = 64; s > 0; s >>= 1) {
        if (e < s) { rs[e] += rs[e + s]; rh[e] += rh[e + s]; }
        __syncthreads();
    }
    if (e == 0) {
        out[GG * 10 + g] = rs[0] + db[0];
        out[GG * 10 + GG + g] = rh[0] + db[0];
    }
}

// ---------------- classification head (mean inline) ----------------
__global__ void head_kernel(const float* __restrict__ poolA, const float* __restrict__ poolB,
                            const float* __restrict__ cnt,
                            const float* __restrict__ w1, const float* __restrict__ b1,
                            const float* __restrict__ w2, const float* __restrict__ b2,
                            float* __restrict__ out) {
    int g = blockIdx.x, j = threadIdx.x;   // 128 threads
    __shared__ float s1[128];
    __shared__ float s2[10];
    __shared__ float lse;
    float invc = 1.f / fmaxf(cnt[g], 1.f);
    const float* ma = poolA + g * 128;
    const float* px = poolB + g * 128;
    float acc = b1[j];
    for (int k = 0; k < 128; ++k) acc += ma[k] * invc * w1[k * 128 + j];
    for (int k = 0; k < 128; ++k) acc += px[k] * invc * w1[(128 + k) * 128 + j];
    s1[j] = fmaxf(acc, 0.f);
    __syncthreads();
    if (j < 10) {
        float a = b2[j];
        for (int k = 0; k < 128; ++k) a += s1[k] * w2[k * 10 + j];
        s2[j] = a;
    }
    __syncthreads();
    if (j == 0) {
        float m = s2[0];
        for (int o = 1; o < 10; ++o) m = fmaxf(m, s2[o]);
        float se = 0.f;
        for (int o = 0; o < 10; ++o) se += expf(s2[o] - m);
        lse = m + logf(se);
    }
    __syncthreads();
    if (j < 10) out[g * 10 + j] = s2[j] - lse;
}

extern "C" void kernel_launch(void* const* d_in, const int* in_sizes, int n_in,
                              void* d_out, int out_size, void* d_ws, size_t ws_size,
                              hipStream_t stream) {
    const float* x     = (const float*)d_in[0];
    const int*   ei    = (const int*)d_in[1];
    const int*   batch = (const int*)d_in[2];
    const float* W1a = (const float*)d_in[3];
    const float* b1a = (const float*)d_in[4];
    const float* W2a = (const float*)d_in[5];
    const float* b2a = (const float*)d_in[6];
    const float* ga  = (const float*)d_in[7];
    const float* bta = (const float*)d_in[8];
    const float* W1b = (const float*)d_in[9];
    const float* b1b = (const float*)d_in[10];
    const float* W2b = (const float*)d_in[11];
    const float* b2b = (const float*)d_in[12];
    const float* gb  = (const float*)d_in[13];
    const float* btb = (const float*)d_in[14];
    const float* lin1_w = (const float*)d_in[15];
    const float* lin1_b = (const float*)d_in[16];
    const float* lin2_w = (const float*)d_in[17];
    const float* lin2_b = (const float*)d_in[18];
    const float* disc_w = (const float*)d_in[19];
    const float* disc_b = (const float*)d_in[20];
    float* out = (float*)d_out;

    const int* src = ei;
    const int* dst = ei + EE;

    // ---- workspace layout ----
    size_t o = 0;
    auto take = [&](size_t b) { size_t p = o; o = (o + b + 255) & ~(size_t)255; return p; };
    uint8_t* w = (uint8_t*)d_ws;
    size_t o_x8   = take((size_t)NN * 128);       // int8 x
    size_t o_sc0  = take((size_t)NN * 4);         // per-row |x| scales
    size_t o_g0   = take((size_t)NN * 128 * 2);   // shared layer-0 gather (bf16)
    size_t o_bufP = take((size_t)NN * 256 * 2);   // concat layer-2 output (bf16)
    size_t o_gbuf = take((size_t)NN * 256 * 2);   // concat gathered (bf16)
    size_t o_y8   = take((size_t)NN * 256);       // uint8 quantized layer outputs
    size_t o_scal = take((size_t)NN * 2 * 4);     // per-row per-branch scales
    size_t o_wf   = take((size_t)12 * MAT_STRIDE * 2);
    size_t o_col  = take((size_t)NBUCK * BCAP * 4);
    size_t o_part = take((size_t)NBUCK * BCAP * 4);
    size_t o_rowpair = take((size_t)NN * 8);
    size_t zero_begin = o;
    size_t o_bcnt   = take((size_t)NBUCK * 4);
    size_t o_stats  = take((size_t)6 * 256 * 4);
    size_t o_cnt    = take(GG * 4);
    size_t o_poolA  = take((size_t)GG * 128 * 4);
    size_t o_poolB  = take((size_t)GG * 128 * 4);
    size_t zero_end = o;

    unsigned short* x8 = (unsigned short*)(w + o_x8);
    float* sc0 = (float*)(w + o_sc0);
    uint32* g0 = (uint32*)(w + o_g0);
    unsigned short* bufP = (unsigned short*)(w + o_bufP);
    unsigned short* gbuf = (unsigned short*)(w + o_gbuf);
    unsigned char* y8 = (unsigned char*)(w + o_y8);
    float* scales = (float*)(w + o_scal);
    unsigned short* wf = (unsigned short*)(w + o_wf);
    int* col = (int*)(w + o_col);
    uint32* part = (uint32*)(w + o_part);
    int2* rowpair = (int2*)(w + o_rowpair);
    int* bcnt = (int*)(w + o_bcnt);
    float* stats = (float*)(w + o_stats);
    float* cnt = (float*)(w + o_cnt);
    float* poolA = (float*)(w + o_poolA);
    float* poolB = (float*)(w + o_poolB);

    hipMemsetAsync(w + zero_begin, 0, zero_end - zero_begin, stream);

    // conversions (independent of CSR)
    x_to_i8_kernel<<<(NN * 64 + 255) / 256, 256, 0, stream>>>(x, x8, sc0);
    convert_w_kernel<<<(24576 + 255) / 256, 256, 0, stream>>>(W1a, W2a, W1b, W2b, wf);

    // CSR build (bucketed, no global scan)
    partition_kernel<<<(EE + PART_CHUNK - 1) / PART_CHUNK, 256, 0, stream>>>(src, dst, bcnt, part);
    build_col_kernel<<<NBUCK, 256, 0, stream>>>(part, bcnt, col, rowpair);
    counts_kernel<<<(NN + 255) / 256, 256, 0, stream>>>(batch, cnt, NN);

    int gatherBlocks = (NN + 3) / 4;   // 4 node-waves per block
    dim3 mlpGrid((NN + 63) / 64, 2);

    // shared layer-0 gather (int8 x input, bf16 out)
    gather0_kernel<<<gatherBlocks, 256, 0, stream>>>((const uint32*)x8, sc0, rowpair, col, (uint2*)g0);

    // layer 0 (both branches read g0) -> uint8
    mlp_dual_kernel<<<mlpGrid, 256, 0, stream>>>(
        (const unsigned short*)g0, 128, 0, wf, b1a, b1b, b2a, b2b, 0, 1,
        nullptr, y8, scales, stats, NN);
    // layer 1
    gather_dual_kernel<<<gatherBlocks, 256, 0, stream>>>(
        (const uint32*)y8, scales, rowpair, col, stats, ga, bta, gb, btb, 0, (uint2*)gbuf);
    mlp_dual_kernel<<<mlpGrid, 256, 0, stream>>>(
        gbuf, 256, 128, wf, b1a, b1b, b2a, b2b, 1, 1,
        nullptr, y8, scales, stats, NN);
    // layer 2 (bf16 out for pooling)
    gather_dual_kernel<<<gatherBlocks, 256, 0, stream>>>(
        (const uint32*)y8, scales, rowpair, col, stats, ga, bta, gb, btb, 1, (uint2*)gbuf);
    mlp_dual_kernel<<<mlpGrid, 256, 0, stream>>>(
        gbuf, 256, 128, wf, b1a, b1b, b2a, b2b, 2, 0,
        bufP, nullptr, nullptr, stats, NN);

    pool_dual_kernel<<<(NN + POOL_CHUNK - 1) / POOL_CHUNK, 256, 0, stream>>>(
        bufP, stats, ga, bta, gb, btb, batch, poolA, poolB, NN);
    disc_kernel<<<GG, 128, 0, stream>>>(poolB, cnt, disc_w, disc_b, out);
    head_kernel<<<GG, 128, 0, stream>>>(poolA, poolB, cnt, lin1_w, lin1_b, lin2_w, lin2_b, out);
}